// Round 13
// baseline (340.428 us; speedup 1.0000x reference)
//
#include <hip/hip_runtime.h>
#include <hip/hip_cooperative_groups.h>
#include <stdint.h>

// Exact fp32 reproduction of the numpy reference requires no FMA contraction
// and identical association order everywhere below.
#pragma clang fp contract(off)

namespace cg = cooperative_groups;

#define B_    4
#define NV_   6890
#define NF_   27552     // 2*13776
#define IMG_  128
#define UV_   256
#define NPIX  (IMG_*IMG_)

#define TS_     8                 // tile edge in pixels
#define TPB_    (IMG_/TS_)        // 16 tiles per row/col
#define NTILE_  (TPB_*TPB_)       // 256 tiles per batch
#define NBIN_   (B_*NTILE_)       // 1024 bins
#define NZ_     8                 // z-strata per bin (list is bucket-sorted)
#define NCELL_  (NTILE_*NZ_)      // 2048 cells per batch
#define LIST_CAP (1536*1024)      // entries total; per-batch partitioned
#define CAPB_   (LIST_CAP/B_)     // 384K entries per batch (need ~225K)
#define MAXCB_  (CAPB_/256 + NTILE_)  // 1792 phase-B chunks per batch
#define SEEDN_  256               // phase-A entries per bin (nearest-z)
#define NBLK2_  ((NF_+1023)/1024) // 27 face-chunks of 1024 per batch

// Workspace carve ~9.2 MB (<= 11.7 MB proven envelope).

// ------------------------------------------------------------ shared helpers
struct FaceBin {
  int valid, tx0, tx1, ty0, ty1, bu;
  float d21x, d21y, d02x, d02y, d10x, d10y;
  float x0, y0, x1, y1, x2, y2, zmin;
};

__device__ __forceinline__ FaceBin face_bin(
    const float* __restrict__ cam, const float* __restrict__ vp,
    const int* __restrict__ faces, int b, int f) {
  FaceBin r; r.valid = 0; r.zmin = 0.0f;
  int ia = faces[f * 3 + 0], ib = faces[f * 3 + 1], ic = faces[f * 3 + 2];
  const float* vb = vp + (size_t)b * NV_ * 4;
  float x0 = vb[ia * 4 + 0], y0 = vb[ia * 4 + 1], z0 = vb[ia * 4 + 2];
  float x1 = vb[ib * 4 + 0], y1 = vb[ib * 4 + 1], z1 = vb[ib * 4 + 2];
  float x2 = vb[ic * 4 + 0], y2 = vb[ic * 4 + 1], z2 = vb[ic * 4 + 2];
  float area_c = (x1 - x0) * (y2 - y0) - (y1 - y0) * (x2 - x0);
  if (area_c < -1e-3f) return r;
  float xmn = fminf(x0, fminf(x1, x2)), xmx = fmaxf(x0, fmaxf(x1, x2));
  float ymn = fminf(y0, fminf(y1, y2)), ymx = fmaxf(y0, fmaxf(y1, y2));
  int jlo = (int)floorf((xmn + 1.0f) * 64.0f - 0.5f) - 1;
  int jhi = (int)ceilf ((xmx + 1.0f) * 64.0f - 0.5f) + 1;
  int ilo = (int)floorf((1.0f - ymx) * 64.0f - 0.5f) - 1;
  int ihi = (int)ceilf ((1.0f - ymn) * 64.0f - 0.5f) + 1;
  if (jhi < 0 || ihi < 0 || jlo > IMG_ - 1 || ilo > IMG_ - 1) return r;
  jlo = max(jlo, 0); ilo = max(ilo, 0);
  jhi = min(jhi, IMG_ - 1); ihi = min(ihi, IMG_ - 1);
  r.tx0 = jlo >> 3; r.tx1 = jhi >> 3; r.ty0 = ilo >> 3; r.ty1 = ihi >> 3;
  r.zmin = fminf(z0, fminf(z1, z2));
  float tz = 500.0f / (64.0f * cam[b * 3]);
  float zr = r.zmin - tz;   // ~N(-0.254, 0.168): octile edges below
  r.bu = (zr > -0.447f) + (zr > -0.367f) + (zr > -0.308f) + (zr > -0.254f) +
         (zr > -0.200f) + (zr > -0.141f) + (zr > -0.061f);
  r.d21x = x2 - x1; r.d21y = y2 - y1;
  r.d02x = x0 - x2; r.d02y = y0 - y2;
  r.d10x = x1 - x0; r.d10y = y1 - y0;
  r.x0 = x0; r.y0 = y0; r.x1 = x1; r.y1 = y1; r.x2 = x2; r.y2 = y2;
  r.valid = 1;
  return r;
}

// Conservative tile-overlap: evaluate each edge at its argmax corner of the
// tile's pixel-center box; reject only if provably negative everywhere.
__device__ __forceinline__ int tile_pass(const FaceBin& r, int tx, int ty) {
  float pxmin = fmaf((float)(tx * 8), 0.015625f, -0.9921875f);
  float pxmax = pxmin + 0.109375f;
  float pymax = fmaf((float)(ty * 8), -0.015625f, 0.9921875f);
  float pymin = pymax - 0.109375f;
  float w0m = r.d21x * ((r.d21x > 0.0f ? pymax : pymin) - r.y1) -
              r.d21y * ((r.d21y > 0.0f ? pxmin : pxmax) - r.x1);
  float w1m = r.d02x * ((r.d02x > 0.0f ? pymax : pymin) - r.y2) -
              r.d02y * ((r.d02y > 0.0f ? pxmin : pxmax) - r.x2);
  float w2m = r.d10x * ((r.d10x > 0.0f ? pymax : pymin) - r.y0) -
              r.d10y * ((r.d10y > 0.0f ? pxmin : pxmax) - r.x0);
  return (w0m >= -1e-3f) && (w1m >= -1e-3f) && (w2m >= -1e-3f);
}

// raster_slice: R6/R2/R3-validated exact-deferral pass (unchanged semantics).
// F must be WAVE-PRIVATE (the R12 bug was sharing it across waves).
template <int S>
__device__ __forceinline__ void raster_slice(
    const float4 (*F)[S], int nsurv, float px, float py,
    unsigned long long& kb, unsigned& kbz_u) {
  unsigned win_u = 0x7F800000u;
  unsigned long long qm = 0ull;
  for (int q = 0; q < nsurv; ++q) {
    float4 A = F[0][q];
    float4 Bv = F[1][q];
    float4 Cv = F[2][q];
    float w0 = A.x * (py - A.w) - A.y * (px - A.z);
    float w1 = Bv.x * (py - Bv.w) - Bv.y * (px - Bv.z);
    float w2 = Cv.x * (py - Cv.w) - Cv.y * (px - Cv.z);
    float area = (w0 + w1) + w2;
    float mn = fminf(w0, fminf(w1, w2));
    bool pred = (area > 0.0f) && !(mn < 0.0f);
    if (!__any(pred)) continue;
    float4 P = F[4][q];
    float num = (w0 * P.x + w1 * P.y) + w2 * P.z;
    float zpa = (area * P.w) * __builtin_amdgcn_rcpf(num);
    unsigned cu = win_u < kbz_u ? win_u : kbz_u;
    float thrq = __uint_as_float(cu) * 1.001f;
    bool amb = pred && (!(zpa > thrq) ||
                        (zpa > 0.09989f && zpa < 0.10011f) ||
                        (zpa > 24.9724f && zpa < 25.0276f));
    if (amb) qm |= 1ull << q;
    bool ok = pred && (zpa > 0.1001f) && (zpa < 24.975f);
    unsigned zb = __float_as_uint(zpa);
    if (ok && zb < win_u) win_u = zb;
  }
  while (__any(qm != 0ull)) {
    if (qm != 0ull) {
      int q = __ffsll(qm) - 1;
      qm &= qm - 1ull;
      float4 A = F[0][q];
      float4 Bv = F[1][q];
      float4 Cv = F[2][q];
      float w0 = A.x * (py - A.w) - A.y * (px - A.z);
      float w1 = Bv.x * (py - Bv.w) - Bv.y * (px - Bv.z);
      float w2 = Cv.x * (py - Cv.w) - Cv.y * (px - Cv.z);
      float area = (w0 + w1) + w2;
      float4 P = F[4][q];
      float num = (w0 * P.x + w1 * P.y) + w2 * P.z;
      float zpa = (area * P.w) * __builtin_amdgcn_rcpf(num);
      unsigned cu = win_u < kbz_u ? win_u : kbz_u;
      float thrf = __uint_as_float(cu) * 1.001f;
      if (!(zpa > thrf) ||
          (zpa > 0.09989f && zpa < 0.10011f) ||
          (zpa > 24.9724f && zpa < 25.0276f)) {
        float4 Z = F[3][q];
        float b0 = w0 / area, b1 = w1 / area, b2 = w2 / area;
        float invz = (b0 / Z.x + b1 / Z.y) + b2 / Z.z;
        float zp = 1.0f / (invz == 0.0f ? 1.0f : invz);
        if (zp > 0.1f && zp < 25.0f) {
          unsigned long long key =
              ((unsigned long long)__float_as_uint(zp) << 32) |
              (unsigned int)__float_as_int(Z.w);
          if (key < kb) {
            kb = key;
            kbz_u = (unsigned)(kb >> 32);
          }
        }
      }
    }
  }
}

template <int S>
__device__ __forceinline__ void stage_face(
    float4 (*F)[S], const float* __restrict__ vb,
    const int* __restrict__ faces, int fid, int rank) {
  int ia = faces[fid * 3 + 0], ib = faces[fid * 3 + 1], ic = faces[fid * 3 + 2];
  float4 v0 = *(const float4*)(vb + (size_t)ia * 4);
  float4 v1 = *(const float4*)(vb + (size_t)ib * 4);
  float4 v2 = *(const float4*)(vb + (size_t)ic * 4);
  F[0][rank] = make_float4(v2.x - v1.x, v2.y - v1.y, v1.x, v1.y);  // d21, v1
  F[1][rank] = make_float4(v0.x - v2.x, v0.y - v2.y, v2.x, v2.y);  // d02, v2
  F[2][rank] = make_float4(v1.x - v0.x, v1.y - v0.y, v0.x, v0.y);  // d10, v0
  F[3][rank] = make_float4(v0.z, v1.z, v2.z, __int_as_float(fid));
  F[4][rank] =
      make_float4(v1.z * v2.z, v0.z * v2.z, v0.z * v1.z, v0.z * v1.z * v2.z);
}

#define TAP(ty, tx, wexpr)                                                   \
  {                                                                          \
    int ty_ = (ty), tx_ = (tx);                                              \
    float w_ = (wexpr);                                                      \
    float valid_ =                                                           \
        (tx_ >= 0 && tx_ < UV_ && ty_ >= 0 && ty_ < UV_) ? 1.0f : 0.0f;      \
    float wv_ = w_ * valid_;                                                 \
    int cy_ = min(max(ty_, 0), UV_ - 1), cx_ = min(max(tx_, 0), UV_ - 1);    \
    int o_ = cy_ * UV_ + cx_;                                                \
    cr = cr + img[o_] * wv_;                                                 \
    cg = cg + img[UV_ * UV_ + o_] * wv_;                                     \
    cb = cb + img[2 * UV_ * UV_ + o_] * wv_;                                 \
  }

// ------------------------------------------------------------- mega kernel
// R13: whole pipeline in ONE cooperative kernel, 256 blocks x 1024 thr.
// grid.sync() between phases replaces 6 kernel boundaries. Phase bodies are
// the validated R9-R11 kernels re-indexed to block-stride tasks. R12's P6
// bug (staging shared across waves) fixed: staging is wave-private
// fd[16][5][32]; each half-block (8 waves x 32 entries) owns one chunk.
extern "C" __global__ void __launch_bounds__(1024) mega_k(
    const float* __restrict__ cam, const float* __restrict__ verts,
    const float* __restrict__ uv, const float* __restrict__ samp,
    const int* __restrict__ faces, unsigned long long* __restrict__ zkey,
    float* __restrict__ vp, int* __restrict__ off8, int* __restrict__ binoff,
    int* __restrict__ bintot, int* __restrict__ work, int* __restrict__ nC,
    ulonglong2* __restrict__ recs, unsigned short* __restrict__ cntb,
    int* __restrict__ list, float* __restrict__ out) {
  cg::grid_group gg = cg::this_grid();
  __shared__ __align__(16) char smem[49152];
  int blk = blockIdx.x;
  int t = threadIdx.x;

  // ---- P1: projection (vp float4-padded)
  {
    int idx = blk * 1024 + t;
    if (idx < B_ * NV_) {
      int b = idx / NV_;
      float c0 = cam[b * 3 + 0], c1 = cam[b * 3 + 1], c2 = cam[b * 3 + 2];
      float tz = 500.0f / (64.0f * c0);
      const float* src = verts + (size_t)idx * 3;
      float* dst = vp + (size_t)idx * 4;
      dst[0] = c0 * (src[0] + c1);
      dst[1] = c0 * (src[1] + c2);
      dst[2] = src[2] + tz;
      dst[3] = 0.0f;
    }
  }
  gg.sync();

  // ---- P2: facebin — fp ONCE; LDS cell counts; record + count-row dump
  {
    int* scnt = (int*)smem;
    for (int tau = blk; tau < NBLK2_ * B_; tau += 256) {
      int b = tau / NBLK2_, ch = tau - b * NBLK2_;
      int f = ch * 1024 + t;
      for (int k = t; k < NCELL_; k += 1024) scnt[k] = 0;
      __syncthreads();
      if (f < NF_) {
        FaceBin r = face_bin(cam, vp, faces, b, f);
        unsigned long long mask = 0ull;
        unsigned info = 0u;
        float zmin = 0.0f;
        if (r.valid) {
          int w = r.tx1 - r.tx0 + 1, h = r.ty1 - r.ty0 + 1;
          bool full = (w * h > 64);
          int k = 0;
          for (int ty = r.ty0; ty <= r.ty1; ++ty)
            for (int tx = r.tx0; tx <= r.tx1; ++tx, ++k)
              if (full || tile_pass(r, tx, ty)) {
                if (!full) mask |= 1ull << k;
                atomicAdd(&scnt[(ty * TPB_ + tx) * NZ_ + r.bu], 1);
              }
          if (full) mask = ~0ull;
          if (mask != 0ull) {
            info = 0x80000000u | ((unsigned)r.bu << 28) |
                   ((unsigned)r.tx0 << 24) | ((unsigned)r.ty0 << 20) |
                   ((unsigned)(w - 1) << 16) | ((unsigned)(h - 1) << 12);
            zmin = r.zmin;
          }
        }
        ulonglong2 rr;
        rr.x = mask;
        rr.y = ((unsigned long long)info << 32) |
               (unsigned)__float_as_uint(zmin);
        recs[(size_t)b * NF_ + f] = rr;
      }
      __syncthreads();
      unsigned short* dst = cntb + ((size_t)b * NBLK2_ + ch) * NCELL_;
      for (int k = t; k < NCELL_; k += 1024)
        dst[k] = (unsigned short)scnt[k];   // <= 1024 per cell per chunk
      __syncthreads();
    }
  }
  gg.sync();

  // ---- P3: sumscan (4 tasks; verbatim port of sumscan_k, NBLK -> 27)
  if (blk < B_) {
    int* tot = (int*)smem;
    int* wsum = (int*)(smem + 8192);
    int* half0 = (int*)(smem + 8256);
    int* nchs = (int*)(smem + 8272);
    int b = blk;
    int lane = t & 63, w = t >> 6;
    for (int c = t; c < NCELL_; c += 1024) {
      int run = 0;
      for (int q = 0; q < NBLK2_; ++q) {
        size_t o = ((size_t)b * NBLK2_ + q) * NCELL_ + c;
        int v = (int)cntb[o];
        cntb[o] = (unsigned short)run;
        run += v;
      }
      tot[c] = run;
    }
    __syncthreads();
    int base = b * CAPB_;
    int v0 = tot[t];
    int inc0 = v0;
    for (int d = 1; d < 64; d <<= 1) {
      int u = __shfl_up(inc0, d, 64);
      if (lane >= d) inc0 += u;
    }
    if (lane == 63) wsum[w] = inc0;
    __syncthreads();
    int wb0 = 0;
    for (int k = 0; k < 16; ++k) wb0 += (k < w) ? wsum[k] : 0;
    off8[(size_t)b * NCELL_ + t] = base + wb0 + inc0 - v0;
    if (t == 1023) half0[0] = wb0 + inc0;
    __syncthreads();
    int v1 = tot[1024 + t];
    int inc1 = v1;
    for (int d = 1; d < 64; d <<= 1) {
      int u = __shfl_up(inc1, d, 64);
      if (lane >= d) inc1 += u;
    }
    if (lane == 63) wsum[w] = inc1;
    __syncthreads();
    int wb1 = 0;
    for (int k = 0; k < 16; ++k) wb1 += (k < w) ? wsum[k] : 0;
    off8[(size_t)b * NCELL_ + 1024 + t] = base + half0[0] + wb1 + inc1 - v1;
    __syncthreads();
    if (t < NTILE_) {
      int s = 0;
#pragma unroll
      for (int j = 0; j < NZ_; ++j) s += tot[t * NZ_ + j];
      bintot[b * NTILE_ + t] = s;
      binoff[b * NTILE_ + t] = off8[(size_t)b * NCELL_ + t * NZ_];
      nchs[t] = (max(s - SEEDN_, 0) + 255) >> 8;
    }
    __syncthreads();
    int vc = (t < NTILE_) ? nchs[t] : 0;
    int incc = vc;
    for (int d = 1; d < 64; d <<= 1) {
      int u = __shfl_up(incc, d, 64);
      if (lane >= d) incc += u;
    }
    if (t < NTILE_ && lane == 63) wsum[w] = incc;   // w in 0..3
    __syncthreads();
    if (t < NTILE_) {
      int wb = 0;
      for (int k = 0; k < 4; ++k) wb += (k < w) ? wsum[k] : 0;
      int cb = wb + incc - vc;
      if (t == NTILE_ - 1) nC[b] = wb + incc;
      for (int q = 0; q < vc; ++q)
        work[b * MAXCB_ + cb + q] = t | ((q + 1) << 8);   // tile | chunk<<8
    }
  }
  gg.sync();

  // ---- P4: fill — record replay, LDS-only ranks, packed (z16<<15)|fid
  {
    int* lbase = (int*)smem;
    int* lrank = (int*)(smem + 8192);
    for (int tau = blk; tau < NBLK2_ * B_; tau += 256) {
      int b = tau / NBLK2_, ch = tau - b * NBLK2_;
      int f = ch * 1024 + t;
      const unsigned short* prow = cntb + ((size_t)b * NBLK2_ + ch) * NCELL_;
      const int* orow = off8 + (size_t)b * NCELL_;
      for (int k = t; k < NCELL_; k += 1024) {
        lbase[k] = orow[k] + (int)prow[k];
        lrank[k] = 0;
      }
      __syncthreads();
      if (f < NF_) {
        ulonglong2 rr = recs[(size_t)b * NF_ + f];
        unsigned long long mask = rr.x;
        unsigned info = (unsigned)(rr.y >> 32);
        unsigned z16 = ((unsigned)rr.y) >> 16;
        if (info >> 31) {
          int ev = (int)((z16 << 15) | (unsigned)f);
          int bu = (info >> 28) & 7;
          int tx0 = (info >> 24) & 15, ty0 = (info >> 20) & 15;
          int w = ((info >> 16) & 15) + 1, h = ((info >> 12) & 15) + 1;
          bool full = (w * h > 64);
          int cap = (b + 1) * CAPB_;
          int k = 0;
          for (int ty = ty0; ty < ty0 + h; ++ty)
            for (int tx = tx0; tx < tx0 + w; ++tx, ++k)
              if (full || ((mask >> k) & 1ull)) {
                int cell = (ty * TPB_ + tx) * NZ_ + bu;
                int rk = atomicAdd(&lrank[cell], 1);
                int slot = lbase[cell] + rk;
                if (slot < cap) list[slot] = ev;
              }
        }
      }
      __syncthreads();
    }
  }
  gg.sync();

  // ---- P5: seed — 4 bins/block, 16 waves x 16 entries (SEEDN=256),
  // WAVE-PRIVATE staging fd16[ws]. Plain store = init + sentinel.
  {
    auto fd16 = (float4 (*)[5][16])smem;                        // [16][5][16]
    auto mg16 = (unsigned long long (*)[64])(smem + 20480);     // [16][64]
    int ws = t >> 6, lane = t & 63;
    for (int rd = 0; rd < 4; ++rd) {
      int bin = blk * 4 + rd;
      int b = bin >> 8;
      int tt = bin & 255;
      int tyT = tt >> 4, txT = tt & 15;
      int pi = tyT * TS_ + (lane >> 3);
      int pj = txT * TS_ + (lane & 7);
      float px = fmaf((float)pj, 0.015625f, -0.9921875f);
      float py = fmaf((float)pi, -0.015625f, 0.9921875f);
      int n = min(bintot[bin], SEEDN_);
      int base = binoff[bin];
      int seg = ws * 16;
      int mw = min(n - seg, 16);
      unsigned long long kb = ~0ull;
      unsigned kbz_u = 0x7F800000u;
      if (mw > 0) {
        if (lane < mw) {
          int fid = (int)((unsigned)list[base + seg + lane] & 0x7FFFu);
          stage_face<16>(fd16[ws], vp + (size_t)b * NV_ * 4, faces, fid,
                         lane);
        }
        raster_slice<16>(fd16[ws], mw, px, py, kb, kbz_u);
      }
      mg16[ws][lane] = kb;
      __syncthreads();
      if (ws == 0) {
        unsigned long long k0 = mg16[0][lane];
#pragma unroll
        for (int j = 1; j < 16; ++j) {
          unsigned long long kj = mg16[j][lane];
          k0 = kj < k0 ? kj : k0;
        }
        zkey[(size_t)b * NPIX + pi * IMG_ + pj] = k0;
      }
      __syncthreads();
    }
  }
  gg.sync();

  // ---- P6: raster — 2 chunks/block/round; each HALF-BLOCK (8 waves x 32
  // entries) owns one 256-entry chunk; staging fd[wsg] is WAVE-PRIVATE
  // (R12 bug fix). B_*MAXCB_ = 7168 = 512*14 -> grid-stride exact, no
  // overflow. Seed prune (validated R9): (e>>15) <= bits(wavemax*1.01)>>16.
  {
    auto fd = (float4 (*)[5][32])smem;                          // [16][5][32]
    auto mg = (unsigned long long (*)[64])(smem + 40960);       // [16][64]
    int h = t >> 9;                  // half 0/1
    int wsg = t >> 6;                // global wave 0..15
    int ws8 = wsg & 7;               // wave within half
    int lane = t & 63;
    const unsigned* zhi = (const unsigned*)zkey;
    for (int g0 = blk * 2; g0 < B_ * MAXCB_; g0 += 512) {
      int g = g0 + h;                              // < 7168 (divisibility)
      int b = g / MAXCB_;
      int i = g - b * MAXCB_;
      bool active = (i < nC[b]);
      unsigned long long kb = ~0ull;
      int pi = 0, pj = 0, bb = 0;
      if (active) {
        int wkv = work[b * MAXCB_ + i];
        int tt = wkv & (NTILE_ - 1);
        int chunk = wkv >> 8;                      // >= 1
        int bin = b * NTILE_ + tt;
        int tyT = tt >> 4, txT = tt & 15;
        pi = tyT * TS_ + (lane >> 3);
        pj = txT * TS_ + (lane & 7);
        bb = b;
        float px = fmaf((float)pj, 0.015625f, -0.9921875f);
        float py = fmaf((float)pi, -0.015625f, 0.9921875f);
        unsigned seed_u = min(
            zhi[((size_t)b * NPIX + pi * IMG_ + pj) * 2 + 1], 0x7F800000u);
        unsigned mx = seed_u;
        for (int j = 1; j < 64; j <<= 1) {
          unsigned o = (unsigned)__shfl_xor((int)mx, j, 64);
          mx = o > mx ? o : mx;
        }
        unsigned thr_code =
            __float_as_uint(__uint_as_float(mx) * 1.01f) >> 16;
        int n = bintot[bin];
        int seg = SEEDN_ + ((chunk - 1) << 8) + (ws8 << 5);   // 32/wave
        int base0 = binoff[bin] + seg;
        int mw = min(n - seg, 32);
        mw = max(mw, 0);
        bool live = false;
        int fid = 0;
        if (lane < mw) {
          unsigned e = (unsigned)list[base0 + lane];
          live = ((e >> 15) <= thr_code);
          fid = (int)(e & 0x7FFFu);
        }
        unsigned long long bal = __ballot(live);
        unsigned kbz_u = seed_u;
        if (bal != 0ull) {
          int nsurv = (int)__popcll(bal);
          int rank = (int)__popcll(bal & ((1ull << lane) - 1ull));
          if (live)
            stage_face<32>(fd[wsg], vp + (size_t)b * NV_ * 4, faces, fid,
                           rank);
          raster_slice<32>(fd[wsg], nsurv, px, py, kb, kbz_u);
        }
      }
      mg[wsg][lane] = kb;
      __syncthreads();
      if (active && ws8 == 0) {
        unsigned long long k0 = mg[h * 8 + 0][lane];
#pragma unroll
        for (int j = 1; j < 8; ++j) {
          unsigned long long kj = mg[h * 8 + j][lane];
          k0 = kj < k0 ? kj : k0;
        }
        if (k0 != ~0ull)
          atomicMin(zkey + (size_t)bb * NPIX + pi * IMG_ + pj, k0);
      }
      __syncthreads();
    }
  }
  gg.sync();

  // ---- P7: shade (lazy texture fetch; lighting multiplier == 1.0)
  {
    int idx = blk * 1024 + t;
    if (idx < B_ * NPIX) {
      int b = idx / NPIX;
      int p = idx - b * NPIX;
      int ii = p / IMG_;
      int jj = p - ii * IMG_;
      unsigned long long key = zkey[idx];
      float cr = 0.0f, cg2 = 0.0f, cb2 = 0.0f;
      float& cg = cg2;
      float& cb = cb2;
      if (key != 0xFFFFFFFFFFFFFFFFull) {
        int f = (int)(key & 0xFFFFFFFFull);
        int ia = faces[f * 3 + 0], ib = faces[f * 3 + 1],
            ic = faces[f * 3 + 2];
        const float* vb = vp + (size_t)b * NV_ * 4;
        float x0 = vb[ia * 4 + 0], y0 = vb[ia * 4 + 1];
        float x1 = vb[ib * 4 + 0], y1 = vb[ib * 4 + 1];
        float x2 = vb[ic * 4 + 0], y2 = vb[ic * 4 + 1];
        float px = (float)(2 * jj + 1) / 128.0f - 1.0f;
        float py = 1.0f - (float)(2 * ii + 1) / 128.0f;
        float w0 = (x2 - x1) * (py - y1) - (y2 - y1) * (px - x1);
        float w1 = (x0 - x2) * (py - y2) - (y0 - y2) * (px - x2);
        float w2 = (x1 - x0) * (py - y0) - (y1 - y0) * (px - x0);
        float area = (w0 + w1) + w2;
        float s = (area == 0.0f) ? 1.0f : area;
        float b0 = w0 / s, b1 = w1 / s;
        int t0 = min(max((int)floorf(b0 * 3.0f), 0), 2);
        int t1 = min(max((int)floorf(b1 * 3.0f), 0), 2);
        const float* g = samp + ((size_t)f * 9 + (size_t)(t0 * 3 + t1)) * 2;
        float gx = g[0], gy = g[1];
        float x = (gx + 1.0f) * 128.0f - 0.5f;
        float y = (gy + 1.0f) * 128.0f - 0.5f;
        float x0f = floorf(x), y0f = floorf(y);
        float wx = x - x0f, wy = y - y0f;
        int xi = (int)x0f, yi = (int)y0f;
        float omwx = 1.0f - wx, omwy = 1.0f - wy;
        const float* img = uv + (size_t)b * 3 * UV_ * UV_;
        TAP(yi,     xi,     omwx * omwy)
        TAP(yi,     xi + 1, wx * omwy)
        TAP(yi + 1, xi,     omwx * wy)
        TAP(yi + 1, xi + 1, wx * wy)
      }
      out[((size_t)b * 3 + 0) * NPIX + p] = cr;
      out[((size_t)b * 3 + 1) * NPIX + p] = cg2;
      out[((size_t)b * 3 + 2) * NPIX + p] = cb2;
    }
  }
}

// ------------------------------------------------------------------- launch
extern "C" void kernel_launch(void* const* d_in, const int* in_sizes, int n_in,
                              void* d_out, int out_size, void* d_ws,
                              size_t ws_size, hipStream_t stream) {
  const float* cam   = (const float*)d_in[0];
  const float* verts = (const float*)d_in[1];
  const float* uv    = (const float*)d_in[2];
  const float* samp  = (const float*)d_in[3];
  const int*   faces = (const int*)d_in[4];
  float* outp = (float*)d_out;

  char* ws = (char*)d_ws;
  size_t o = 0;
  unsigned long long* zkey = (unsigned long long*)(ws + o);
  o += (size_t)B_ * NPIX * 8;                                   // 512 KB
  float* vp = (float*)(ws + o);
  o += ((size_t)B_ * NV_ * 4 * 4 + 1023) & ~1023ull;            // ~441 KB
  int* off8   = (int*)(ws + o); o += (size_t)B_ * NCELL_ * 4;   // 32 KB
  int* binoff = (int*)(ws + o); o += NBIN_ * 4;
  int* bintot = (int*)(ws + o); o += NBIN_ * 4;
  int* nC     = (int*)(ws + o); o += 1024;
  int* work   = (int*)(ws + o); o += (size_t)B_ * MAXCB_ * 4;   // 28 KB
  ulonglong2* recs = (ulonglong2*)(ws + o);
  o += (size_t)B_ * NF_ * 16;                                   // ~1.76 MB
  unsigned short* cntb = (unsigned short*)(ws + o);
  o += (size_t)B_ * NBLK2_ * NCELL_ * 2;                        // ~442 KB
  int* list = (int*)(ws + o);                                   // 6 MB
  // total ~9.2 MB — within the <=11.7 MB proven envelope.

  void* args[] = {(void*)&cam,    (void*)&verts, (void*)&uv,
                  (void*)&samp,   (void*)&faces, (void*)&zkey,
                  (void*)&vp,     (void*)&off8,  (void*)&binoff,
                  (void*)&bintot, (void*)&work,  (void*)&nC,
                  (void*)&recs,   (void*)&cntb,  (void*)&list,
                  (void*)&outp};
  hipLaunchCooperativeKernel((const void*)mega_k, dim3(256), dim3(1024),
                             args, 0, stream);
}

// Round 14
// 180.662 us; speedup vs baseline: 1.8843x; 1.8843x over previous
//
#include <hip/hip_runtime.h>
#include <stdint.h>

// Exact fp32 reproduction of the numpy reference requires no FMA contraction
// and identical association order everywhere below.
#pragma clang fp contract(off)

#define B_    4
#define NV_   6890
#define NF_   27552     // 2*13776
#define IMG_  128
#define UV_   256
#define NPIX  (IMG_*IMG_)

#define TS_     8                 // tile edge in pixels
#define TPB_    (IMG_/TS_)        // 16 tiles per row/col
#define NTILE_  (TPB_*TPB_)       // 256 tiles per batch
#define NBIN_   (B_*NTILE_)       // 1024 bins
#define NZ_     8                 // z-strata per bin (list is bucket-sorted)
#define NCELL_  (NTILE_*NZ_)      // 2048 cells per batch
#define LIST_CAP (1536*1024)      // entries; edge-filtered need ~0.9M
#define MAXC_   (LIST_CAP/256 + NBIN_)  // 7168: bound on phase-B chunks
#define FBF_    256               // faces per binning block
#define NBLK_   ((NF_+FBF_-1)/FBF_)   // 108 binning blocks per batch

// Workspace budget note (R9/R14): total carve = 10.39 MB. R7 (22.3 MB) and
// R8 (13.4 MB) both died in container; all passing versions were <= 11.7 MB.
// Keep the carve under ~11 MB.
//
// R14 session conclusion: this is the R9 champion restored verbatim.
// Measured plateau ~182 us. Refuted alternatives: per-kernel micro-opts
// (R10/R11 flat), cooperative mega-fusion (R13: 265 us, grid.sync +
// one-shape-fits-all occupancy loss). Every constituent kernel < 40 us,
// none BW- or VALU-saturated: latency / sum-of-work plateau.

// ---------------------------------------------------------------- projection
// vp is float4-padded: one dwordx4 per vertex gather downstream.
__global__ void __launch_bounds__(256) project_k(
    const float* __restrict__ cam, const float* __restrict__ verts,
    float* __restrict__ vp) {
  int idx = blockIdx.x * 256 + threadIdx.x;
  if (idx >= B_ * NV_) return;
  int b = idx / NV_;
  float c0 = cam[b * 3 + 0], c1 = cam[b * 3 + 1], c2 = cam[b * 3 + 2];
  float tz = 500.0f / (64.0f * c0);                  // FLENGTH/(p*cam0), p=64
  const float* src = verts + (size_t)idx * 3;
  float* dst = vp + (size_t)idx * 4;
  dst[0] = c0 * (src[0] + c1);
  dst[1] = c0 * (src[1] + c2);
  dst[2] = src[2] + tz;
  dst[3] = 0.0f;
}

// ------------------------------------------------------------------- binning
// Per (face,batch): backface cull (area_c < -1e-3, R1-validated), bbox(+-1px),
// per-tile CONSERVATIVE edge test (max over the tile's pixel-center box of
// each edge fn >= -1e-3; fp errors ~1e-5 -> any fp-acceptable pixel keeps its
// tile). z-bucket from exact zmin relative to tz (load-balance only).
// fp runs ONCE (facebin_k): counts into LDS, dumps the per-block count row
// NON-atomically; sum_k converts rows IN PLACE to per-block exclusive
// prefixes + cell totals; fill replays the record with LDS-only ranks.
// No global atomics anywhere in binning; count==fill by construction.
struct FaceBin {
  int valid, tx0, tx1, ty0, ty1, bu;
  float d21x, d21y, d02x, d02y, d10x, d10y;
  float x0, y0, x1, y1, x2, y2, zmin;
};

__device__ __forceinline__ FaceBin face_bin(
    const float* __restrict__ cam, const float* __restrict__ vp,
    const int* __restrict__ faces, int b, int f) {
  FaceBin r; r.valid = 0; r.zmin = 0.0f;
  int ia = faces[f * 3 + 0], ib = faces[f * 3 + 1], ic = faces[f * 3 + 2];
  const float* vb = vp + (size_t)b * NV_ * 4;
  float x0 = vb[ia * 4 + 0], y0 = vb[ia * 4 + 1], z0 = vb[ia * 4 + 2];
  float x1 = vb[ib * 4 + 0], y1 = vb[ib * 4 + 1], z1 = vb[ib * 4 + 2];
  float x2 = vb[ic * 4 + 0], y2 = vb[ic * 4 + 1], z2 = vb[ic * 4 + 2];
  float area_c = (x1 - x0) * (y2 - y0) - (y1 - y0) * (x2 - x0);
  if (area_c < -1e-3f) return r;
  float xmn = fminf(x0, fminf(x1, x2)), xmx = fmaxf(x0, fmaxf(x1, x2));
  float ymn = fminf(y0, fminf(y1, y2)), ymx = fmaxf(y0, fmaxf(y1, y2));
  int jlo = (int)floorf((xmn + 1.0f) * 64.0f - 0.5f) - 1;
  int jhi = (int)ceilf ((xmx + 1.0f) * 64.0f - 0.5f) + 1;
  int ilo = (int)floorf((1.0f - ymx) * 64.0f - 0.5f) - 1;
  int ihi = (int)ceilf ((1.0f - ymn) * 64.0f - 0.5f) + 1;
  if (jhi < 0 || ihi < 0 || jlo > IMG_ - 1 || ilo > IMG_ - 1) return r;
  jlo = max(jlo, 0); ilo = max(ilo, 0);
  jhi = min(jhi, IMG_ - 1); ihi = min(ihi, IMG_ - 1);
  r.tx0 = jlo >> 3; r.tx1 = jhi >> 3; r.ty0 = ilo >> 3; r.ty1 = ihi >> 3;
  r.zmin = fminf(z0, fminf(z1, z2));
  float tz = 500.0f / (64.0f * cam[b * 3]);
  float zr = r.zmin - tz;   // ~N(-0.254, 0.168): octile edges below
  r.bu = (zr > -0.447f) + (zr > -0.367f) + (zr > -0.308f) + (zr > -0.254f) +
         (zr > -0.200f) + (zr > -0.141f) + (zr > -0.061f);
  r.d21x = x2 - x1; r.d21y = y2 - y1;
  r.d02x = x0 - x2; r.d02y = y0 - y2;
  r.d10x = x1 - x0; r.d10y = y1 - y0;
  r.x0 = x0; r.y0 = y0; r.x1 = x1; r.y1 = y1; r.x2 = x2; r.y2 = y2;
  r.valid = 1;
  return r;
}

// Conservative tile-overlap: evaluate each edge at its argmax corner of the
// tile's pixel-center box; reject only if provably negative everywhere.
__device__ __forceinline__ int tile_pass(const FaceBin& r, int tx, int ty) {
  float pxmin = fmaf((float)(tx * 8), 0.015625f, -0.9921875f);
  float pxmax = pxmin + 0.109375f;
  float pymax = fmaf((float)(ty * 8), -0.015625f, 0.9921875f);
  float pymin = pymax - 0.109375f;
  float w0m = r.d21x * ((r.d21x > 0.0f ? pymax : pymin) - r.y1) -
              r.d21y * ((r.d21y > 0.0f ? pxmin : pxmax) - r.x1);
  float w1m = r.d02x * ((r.d02x > 0.0f ? pymax : pymin) - r.y2) -
              r.d02y * ((r.d02y > 0.0f ? pxmin : pxmax) - r.x2);
  float w2m = r.d10x * ((r.d10x > 0.0f ? pymax : pymin) - r.y0) -
              r.d10y * ((r.d10y > 0.0f ? pxmin : pxmax) - r.x0);
  return (w0m >= -1e-3f) && (w1m >= -1e-3f) && (w2m >= -1e-3f);
}

// Record: .x = tile mask (bit k = bbox tile k row-major passes; if w*h > 64
// the mask is ignored and ALL bbox tiles are listed — producer and replayer
// use the same w*h rule, so they agree). .y = info<<32 | bits(zmin).
// info: bit31 valid | bu<<28 | tx0<<24 | ty0<<20 | (w-1)<<16 | (h-1)<<12.
__global__ void __launch_bounds__(FBF_) facebin_k(
    const float* __restrict__ cam, const float* __restrict__ vp,
    const int* __restrict__ faces, ulonglong2* __restrict__ recs,
    unsigned short* __restrict__ cntb) {
  __shared__ int scnt[NCELL_];
  int blk = blockIdx.x, b = blockIdx.y;
  int f = blk * FBF_ + threadIdx.x;
  for (int k = threadIdx.x; k < NCELL_; k += FBF_) scnt[k] = 0;
  __syncthreads();
  if (f < NF_) {
    FaceBin r = face_bin(cam, vp, faces, b, f);
    unsigned long long mask = 0ull;
    unsigned info = 0u;
    float zmin = 0.0f;
    if (r.valid) {
      int w = r.tx1 - r.tx0 + 1, h = r.ty1 - r.ty0 + 1;
      bool full = (w * h > 64);
      int k = 0;
      for (int ty = r.ty0; ty <= r.ty1; ++ty)
        for (int tx = r.tx0; tx <= r.tx1; ++tx, ++k)
          if (full || tile_pass(r, tx, ty)) {
            if (!full) mask |= 1ull << k;
            atomicAdd(&scnt[(ty * TPB_ + tx) * NZ_ + r.bu], 1);
          }
      if (full) mask = ~0ull;
      if (mask != 0ull) {
        info = 0x80000000u | ((unsigned)r.bu << 28) |
               ((unsigned)r.tx0 << 24) | ((unsigned)r.ty0 << 20) |
               ((unsigned)(w - 1) << 16) | ((unsigned)(h - 1) << 12);
        zmin = r.zmin;
      }
    }
    ulonglong2 rr;
    rr.x = mask;
    rr.y = ((unsigned long long)info << 32) | (unsigned)__float_as_uint(zmin);
    recs[(size_t)b * NF_ + f] = rr;
  }
  __syncthreads();
  unsigned short* dst = cntb + ((size_t)b * NBLK_ + blk) * NCELL_;
  for (int k = threadIdx.x; k < NCELL_; k += FBF_)
    dst[k] = (unsigned short)scnt[k];   // per-face-per-cell <= 1 -> <= FBF_
}

// sum_k: per (b,cell), exclusive prefix over the 108 block rows IN PLACE
// (coalesced: consecutive threads = consecutive cells) -> totals in cnt8.
// Prefix values <= cell total <= NF_ < 65536 -> ushort-safe.
__global__ void __launch_bounds__(256) sum_k(
    unsigned short* __restrict__ cntb, int* __restrict__ cnt8) {
  int c = blockIdx.x * 256 + threadIdx.x;
  int b = blockIdx.y;
  int run = 0;
  for (int blk = 0; blk < NBLK_; ++blk) {
    size_t o = ((size_t)b * NBLK_ + blk) * NCELL_ + c;
    int v = (int)cntb[o];
    cntb[o] = (unsigned short)run;
    run += v;
  }
  cnt8[(size_t)b * NCELL_ + c] = run;
}

// Scan 8192 (bin,bucket) cells -> offsets (shuffle-based, 3 barriers);
// derive per-bin base/total and the balanced phase-B chunk work list.
__global__ void __launch_bounds__(1024) scan_k(
    const int* __restrict__ cnt8, int* __restrict__ off8,
    int* __restrict__ binoff, int* __restrict__ bintot,
    int* __restrict__ work, int* __restrict__ nC) {
  __shared__ int wsum[16];
  int t = threadIdx.x;
  int lane = t & 63, w = t >> 6;
  int c[NZ_];
  int s = 0;
#pragma unroll
  for (int j = 0; j < NZ_; ++j) { c[j] = cnt8[t * NZ_ + j]; s += c[j]; }
  int inc = s;
#pragma unroll
  for (int d = 1; d < 64; d <<= 1) {
    int u = __shfl_up(inc, d, 64);
    if (lane >= d) inc += u;
  }
  if (lane == 63) wsum[w] = inc;
  __syncthreads();
  int wb = 0;
  for (int k = 0; k < 16; ++k) wb += (k < w) ? wsum[k] : 0;
  int base = wb + inc - s;
  int o = base;
#pragma unroll
  for (int j = 0; j < NZ_; ++j) {
    off8[t * NZ_ + j] = o;
    o += c[j];
  }
  binoff[t] = base;
  bintot[t] = s;
  int nch = (max(s - 256, 0) + 255) >> 8;   // chunks 1..: entries 256..s
  int inc2 = nch;
#pragma unroll
  for (int d = 1; d < 64; d <<= 1) {
    int u = __shfl_up(inc2, d, 64);
    if (lane >= d) inc2 += u;
  }
  __syncthreads();
  if (lane == 63) wsum[w] = inc2;
  __syncthreads();
  int wb2 = 0;
  for (int k = 0; k < 16; ++k) wb2 += (k < w) ? wsum[k] : 0;
  int cb = wb2 + inc2 - nch;
  if (t == 1023) nC[0] = wb2 + inc2;
  for (int q = 0; q < nch; ++q) work[cb + q] = t | ((q + 1) << 10);
}

// Fill: pure record replay. Block base row = off8 + cntb-prefix
// (deterministic, disjoint across blocks); ranks via LDS atomics only.
// List entry packs (z16 << 15) | fid: z16 = bits(zmin)>>16 (positive float
// -> sign 0 -> 15 significant bits), fid < 32768. Truncation is downward:
// decode(z16) <= zmin, conservative for the hi-z prune.
__global__ void __launch_bounds__(FBF_) bin_fill_k(
    const ulonglong2* __restrict__ recs, const int* __restrict__ off8,
    const unsigned short* __restrict__ cntb, int* __restrict__ list) {
  __shared__ int lbase[NCELL_];
  __shared__ int lrank[NCELL_];
  int blk = blockIdx.x, b = blockIdx.y;
  int f = blk * FBF_ + threadIdx.x;
  const unsigned short* prow = cntb + ((size_t)b * NBLK_ + blk) * NCELL_;
  const int* orow = off8 + (size_t)b * NCELL_;
  for (int k = threadIdx.x; k < NCELL_; k += FBF_) {
    lbase[k] = orow[k] + (int)prow[k];
    lrank[k] = 0;
  }
  __syncthreads();
  if (f < NF_) {
    ulonglong2 rr = recs[(size_t)b * NF_ + f];
    unsigned long long mask = rr.x;
    unsigned info = (unsigned)(rr.y >> 32);
    unsigned z16 = ((unsigned)rr.y) >> 16;
    if (info >> 31) {
      int ev = (int)((z16 << 15) | (unsigned)f);
      int bu = (info >> 28) & 7;
      int tx0 = (info >> 24) & 15, ty0 = (info >> 20) & 15;
      int w = ((info >> 16) & 15) + 1, h = ((info >> 12) & 15) + 1;
      bool full = (w * h > 64);
      int k = 0;
      for (int ty = ty0; ty < ty0 + h; ++ty)
        for (int tx = tx0; tx < tx0 + w; ++tx, ++k)
          if (full || ((mask >> k) & 1ull)) {
            int cell = (ty * TPB_ + tx) * NZ_ + bu;
            int rk = atomicAdd(&lrank[cell], 1);
            int slot = lbase[cell] + rk;
            if (slot < LIST_CAP) list[slot] = ev;
          }
    }
  }
}

// ---------------------------------------------------------------- rasterizer
// raster_slice: R6/R2/R3-validated exact-deferral pass (unchanged semantics).
__device__ __forceinline__ void raster_slice(
    const float4 (*F)[64], int nsurv, float px, float py,
    unsigned long long& kb, unsigned& kbz_u) {
  unsigned win_u = 0x7F800000u;
  unsigned long long qm = 0ull;
  for (int q = 0; q < nsurv; ++q) {
    float4 A = F[0][q];
    float4 Bv = F[1][q];
    float4 Cv = F[2][q];
    float w0 = A.x * (py - A.w) - A.y * (px - A.z);
    float w1 = Bv.x * (py - Bv.w) - Bv.y * (px - Bv.z);
    float w2 = Cv.x * (py - Cv.w) - Cv.y * (px - Cv.z);
    float area = (w0 + w1) + w2;
    float mn = fminf(w0, fminf(w1, w2));
    bool pred = (area > 0.0f) && !(mn < 0.0f);
    if (!__any(pred)) continue;
    float4 P = F[4][q];
    float num = (w0 * P.x + w1 * P.y) + w2 * P.z;
    float zpa = (area * P.w) * __builtin_amdgcn_rcpf(num);
    unsigned cu = win_u < kbz_u ? win_u : kbz_u;
    float thrq = __uint_as_float(cu) * 1.001f;
    bool amb = pred && (!(zpa > thrq) ||
                        (zpa > 0.09989f && zpa < 0.10011f) ||
                        (zpa > 24.9724f && zpa < 25.0276f));
    if (amb) qm |= 1ull << q;
    bool ok = pred && (zpa > 0.1001f) && (zpa < 24.975f);
    unsigned zb = __float_as_uint(zpa);
    if (ok && zb < win_u) win_u = zb;
  }
  while (__any(qm != 0ull)) {
    if (qm != 0ull) {
      int q = __ffsll(qm) - 1;
      qm &= qm - 1ull;
      float4 A = F[0][q];
      float4 Bv = F[1][q];
      float4 Cv = F[2][q];
      float w0 = A.x * (py - A.w) - A.y * (px - A.z);
      float w1 = Bv.x * (py - Bv.w) - Bv.y * (px - Bv.z);
      float w2 = Cv.x * (py - Cv.w) - Cv.y * (px - Cv.z);
      float area = (w0 + w1) + w2;
      float4 P = F[4][q];
      float num = (w0 * P.x + w1 * P.y) + w2 * P.z;
      float zpa = (area * P.w) * __builtin_amdgcn_rcpf(num);
      unsigned cu = win_u < kbz_u ? win_u : kbz_u;
      float thrf = __uint_as_float(cu) * 1.001f;
      if (!(zpa > thrf) ||
          (zpa > 0.09989f && zpa < 0.10011f) ||
          (zpa > 24.9724f && zpa < 25.0276f)) {
        float4 Z = F[3][q];
        float b0 = w0 / area, b1 = w1 / area, b2 = w2 / area;
        float invz = (b0 / Z.x + b1 / Z.y) + b2 / Z.z;
        float zp = 1.0f / (invz == 0.0f ? 1.0f : invz);
        if (zp > 0.1f && zp < 25.0f) {
          unsigned long long key =
              ((unsigned long long)__float_as_uint(zp) << 32) |
              (unsigned int)__float_as_int(Z.w);
          if (key < kb) {
            kb = key;
            kbz_u = (unsigned)(kb >> 32);
          }
        }
      }
    }
  }
}

__device__ __forceinline__ void stage_face(
    float4 (*F)[64], const float* __restrict__ vb,
    const int* __restrict__ faces, int fid, int rank) {
  int ia = faces[fid * 3 + 0], ib = faces[fid * 3 + 1], ic = faces[fid * 3 + 2];
  float4 v0 = *(const float4*)(vb + (size_t)ia * 4);
  float4 v1 = *(const float4*)(vb + (size_t)ib * 4);
  float4 v2 = *(const float4*)(vb + (size_t)ic * 4);
  F[0][rank] = make_float4(v2.x - v1.x, v2.y - v1.y, v1.x, v1.y);  // d21, v1
  F[1][rank] = make_float4(v0.x - v2.x, v0.y - v2.y, v2.x, v2.y);  // d02, v2
  F[2][rank] = make_float4(v1.x - v0.x, v1.y - v0.y, v0.x, v0.y);  // d10, v0
  F[3][rank] = make_float4(v0.z, v1.z, v2.z, __int_as_float(fid));
  F[4][rank] =
      make_float4(v1.z * v2.z, v0.z * v2.z, v0.z * v1.z, v0.z * v1.z * v2.z);
}

// Phase A: one block per bin, FIRST 256 entries — the ~256 NEAREST-z faces
// (bucket order) -> seed ~= final z. Plain store = init + sentinel.
__global__ void __launch_bounds__(256) raster_seed_k(
    const float* __restrict__ vp, const int* __restrict__ faces,
    const int* __restrict__ list, const int* __restrict__ bintot,
    const int* __restrict__ binoff, unsigned long long* __restrict__ zkey) {
  __shared__ float4 fd[4][5][64];
  __shared__ unsigned long long mg[4][64];
  int bin = blockIdx.x;
  int b = bin >> 8;
  int t = bin & 255;
  int tyT = t >> 4, txT = t & 15;
  int ws = threadIdx.x >> 6, lane = threadIdx.x & 63;
  int pi = tyT * TS_ + (lane >> 3);
  int pj = txT * TS_ + (lane & 7);
  float px = fmaf((float)pj, 0.015625f, -0.9921875f);
  float py = fmaf((float)pi, -0.015625f, 0.9921875f);

  int n = min(bintot[bin], 256);
  int base = binoff[bin];
  int seg = ws * 64;
  int mw = min(n - seg, 64);

  unsigned long long kb = ~0ull;
  unsigned kbz_u = 0x7F800000u;
  if (mw > 0) {
    if (lane < mw) {
      int fid = (int)((unsigned)list[base + seg + lane] & 0x7FFFu);
      stage_face(fd[ws], vp + (size_t)b * NV_ * 4, faces, fid, lane);
    }
    // wave-private LDS slice: per-wave in-order DS pipe, no barrier needed
    raster_slice(fd[ws], mw, px, py, kb, kbz_u);
  }

  mg[ws][lane] = kb;
  __syncthreads();
  if (ws == 0) {
    unsigned long long k0 = mg[0][lane];
    unsigned long long k1 = mg[1][lane];
    unsigned long long k2 = mg[2][lane];
    unsigned long long k3 = mg[3][lane];
    k0 = k1 < k0 ? k1 : k0;
    k2 = k3 < k2 ? k3 : k2;
    k0 = k2 < k0 ? k2 : k0;
    zkey[(size_t)b * NPIX + pi * IMG_ + pj] = k0;
  }
}

// Phase B: balanced chunks over entries 256.., seeded from the phase-A
// z-buffer (kernel boundary). Seed read = plain 32-bit load of the hi word:
// zkey is monotone decreasing and every historical value is an exact
// candidate's z, so staleness only weakens the prune, never breaks
// exactness. Prefilter: (e>>15) <= thr_code, thr_code =
// bits(wavemax(seed)*1.01)>>16. skip => zmin_lb > thr*(1-2^-7) >=
// seed*1.002 => exact zp >= zmin*(1-1e-6) > seed strictly => loses to a
// candidate already in zkey (1% margin >> 2^-7 truncation + 1e-5 interp).
// Survivors ballot-compact into the validated slice pass; atomicMin merges.
__global__ void __launch_bounds__(256) raster_k(
    const float* __restrict__ vp, const int* __restrict__ faces,
    const int* __restrict__ list, const int* __restrict__ bintot,
    const int* __restrict__ binoff, const int* __restrict__ work,
    const int* __restrict__ nC, unsigned long long* __restrict__ zkey) {
  __shared__ float4 fd[4][5][64];
  __shared__ unsigned long long mg[4][64];
  int bid = blockIdx.x;
  if (bid >= nC[0]) return;                       // block-uniform exit
  int wkv = work[bid];
  int bin = wkv & (NBIN_ - 1);
  int chunk = wkv >> 10;                          // >= 1
  int b = bin >> 8;
  int t = bin & 255;
  int tyT = t >> 4, txT = t & 15;
  int ws = threadIdx.x >> 6, lane = threadIdx.x & 63;
  int pi = tyT * TS_ + (lane >> 3);
  int pj = txT * TS_ + (lane & 7);
  float px = fmaf((float)pj, 0.015625f, -0.9921875f);
  float py = fmaf((float)pi, -0.015625f, 0.9921875f);

  const unsigned* zhi = (const unsigned*)zkey;
  unsigned seed_u =
      min(zhi[((size_t)b * NPIX + pi * IMG_ + pj) * 2 + 1], 0x7F800000u);
  unsigned mx = seed_u;
  for (int j = 1; j < 64; j <<= 1) {
    unsigned o = (unsigned)__shfl_xor((int)mx, j, 64);
    mx = o > mx ? o : mx;
  }
  unsigned thr_code = __float_as_uint(__uint_as_float(mx) * 1.01f) >> 16;
  // mx = inf -> thr_code 0x7F80 > any real z16 (~0x4100): prune disabled.

  int n = bintot[bin];
  int seg = (chunk << 8) + (ws << 6);
  int base0 = binoff[bin] + seg;
  int mw = min(n - seg, 64);
  mw = max(mw, 0);

  bool live = false;
  int fid = 0;
  if (lane < mw) {
    unsigned e = (unsigned)list[base0 + lane];
    live = ((e >> 15) <= thr_code);
    fid = (int)(e & 0x7FFFu);
  }
  unsigned long long bal = __ballot(live);
  unsigned long long kb = ~0ull;
  unsigned kbz_u = seed_u;          // exact candidate z already in zkey
  if (bal != 0ull) {
    int nsurv = (int)__popcll(bal);
    int rank = (int)__popcll(bal & ((1ull << lane) - 1ull));
    if (live)
      stage_face(fd[ws], vp + (size_t)b * NV_ * 4, faces, fid, rank);
    raster_slice(fd[ws], nsurv, px, py, kb, kbz_u);
  }

  mg[ws][lane] = kb;
  __syncthreads();
  if (ws == 0) {
    unsigned long long k0 = mg[0][lane];
    unsigned long long k1 = mg[1][lane];
    unsigned long long k2 = mg[2][lane];
    unsigned long long k3 = mg[3][lane];
    k0 = k1 < k0 ? k1 : k0;
    k2 = k3 < k2 ? k3 : k2;
    k0 = k2 < k0 ? k2 : k0;
    if (k0 != ~0ull)
      atomicMin(zkey + (size_t)b * NPIX + pi * IMG_ + pj, k0);
  }
}

// ------------------------------------------------------------------- shading
#define TAP(ty, tx, wexpr)                                                   \
  {                                                                          \
    int ty_ = (ty), tx_ = (tx);                                              \
    float w_ = (wexpr);                                                      \
    float valid_ =                                                           \
        (tx_ >= 0 && tx_ < UV_ && ty_ >= 0 && ty_ < UV_) ? 1.0f : 0.0f;      \
    float wv_ = w_ * valid_;                                                 \
    int cy_ = min(max(ty_, 0), UV_ - 1), cx_ = min(max(tx_, 0), UV_ - 1);    \
    int o_ = cy_ * UV_ + cx_;                                                \
    cr = cr + img[o_] * wv_;                                                 \
    cg = cg + img[UV_ * UV_ + o_] * wv_;                                     \
    cb = cb + img[2 * UV_ * UV_ + o_] * wv_;                                 \
  }

__global__ void __launch_bounds__(256) shade_k(
    const float* __restrict__ vp, const int* __restrict__ faces,
    const float* __restrict__ uv, const float* __restrict__ samp,
    const unsigned long long* __restrict__ zkey, float* __restrict__ out) {
  int idx = blockIdx.x * 256 + threadIdx.x;
  if (idx >= B_ * NPIX) return;
  int b = idx / NPIX;
  int p = idx - b * NPIX;
  int ii = p / IMG_;
  int jj = p - ii * IMG_;

  unsigned long long key = zkey[idx];
  float cr = 0.0f, cg = 0.0f, cb = 0.0f;
  if (key != 0xFFFFFFFFFFFFFFFFull) {
    int f = (int)(key & 0xFFFFFFFFull);
    int ia = faces[f * 3 + 0], ib = faces[f * 3 + 1], ic = faces[f * 3 + 2];
    const float* vb = vp + (size_t)b * NV_ * 4;
    float x0 = vb[ia * 4 + 0], y0 = vb[ia * 4 + 1];
    float x1 = vb[ib * 4 + 0], y1 = vb[ib * 4 + 1];
    float x2 = vb[ic * 4 + 0], y2 = vb[ic * 4 + 1];
    float px = (float)(2 * jj + 1) / 128.0f - 1.0f;
    float py = 1.0f - (float)(2 * ii + 1) / 128.0f;
    float w0 = (x2 - x1) * (py - y1) - (y2 - y1) * (px - x1);
    float w1 = (x0 - x2) * (py - y2) - (y0 - y2) * (px - x2);
    float w2 = (x1 - x0) * (py - y0) - (y1 - y0) * (px - x0);
    float area = (w0 + w1) + w2;
    float s = (area == 0.0f) ? 1.0f : area;
    float b0 = w0 / s, b1 = w1 / s;
    int t0 = min(max((int)floorf(b0 * 3.0f), 0), 2);
    int t1 = min(max((int)floorf(b1 * 3.0f), 0), 2);

    // lazy texture fetch: textures[b,f,t0,t1,*,c] == bilinear(uv_imgs[b],
    // sampler[f, t0*3+t1]); lighting multiplier is exactly 1.0 -> skipped.
    const float* g = samp + ((size_t)f * 9 + (size_t)(t0 * 3 + t1)) * 2;
    float gx = g[0], gy = g[1];
    float x = (gx + 1.0f) * 128.0f - 0.5f;   // (g+1)*(W*0.5)-0.5, W=256
    float y = (gy + 1.0f) * 128.0f - 0.5f;
    float x0f = floorf(x), y0f = floorf(y);
    float wx = x - x0f, wy = y - y0f;
    int xi = (int)x0f, yi = (int)y0f;
    float omwx = 1.0f - wx, omwy = 1.0f - wy;
    const float* img = uv + (size_t)b * 3 * UV_ * UV_;
    // reference accumulation order: (y0,x0)+(y0,x0+1)+(y0+1,x0)+(y0+1,x0+1)
    TAP(yi,     xi,     omwx * omwy)
    TAP(yi,     xi + 1, wx * omwy)
    TAP(yi + 1, xi,     omwx * wy)
    TAP(yi + 1, xi + 1, wx * wy)
  }
  out[((size_t)b * 3 + 0) * NPIX + p] = cr;
  out[((size_t)b * 3 + 1) * NPIX + p] = cg;
  out[((size_t)b * 3 + 2) * NPIX + p] = cb;
}

// ------------------------------------------------------------------- launch
extern "C" void kernel_launch(void* const* d_in, const int* in_sizes, int n_in,
                              void* d_out, int out_size, void* d_ws,
                              size_t ws_size, hipStream_t stream) {
  const float* cam   = (const float*)d_in[0];
  const float* verts = (const float*)d_in[1];
  const float* uv    = (const float*)d_in[2];
  const float* samp  = (const float*)d_in[3];
  const int*   faces = (const int*)d_in[4];

  char* ws = (char*)d_ws;
  size_t o = 0;
  unsigned long long* zkey = (unsigned long long*)(ws + o);
  o += (size_t)B_ * NPIX * 8;                                   // 512 KB
  float* vp = (float*)(ws + o);
  o += ((size_t)B_ * NV_ * 4 * 4 + 1023) & ~1023ull;            // ~441 KB
  int* cnt8   = (int*)(ws + o); o += (size_t)B_ * NCELL_ * 4;   // 32 KB
  int* off8   = (int*)(ws + o); o += (size_t)B_ * NCELL_ * 4;   // 32 KB
  int* binoff = (int*)(ws + o); o += NBIN_ * 4;
  int* bintot = (int*)(ws + o); o += NBIN_ * 4;
  int* nC     = (int*)(ws + o); o += 1024;
  int* work   = (int*)(ws + o); o += (size_t)MAXC_ * 4;         // 28 KB
  ulonglong2* recs = (ulonglong2*)(ws + o);
  o += (size_t)B_ * NF_ * 16;                                   // ~1.76 MB
  unsigned short* cntb = (unsigned short*)(ws + o);
  o += (size_t)B_ * NBLK_ * NCELL_ * 2;                         // ~1.77 MB
  int* list = (int*)(ws + o);                                   // 6 MB
  // total ~10.4 MB — within the <=11.7 MB envelope that has passed before.

  project_k<<<(B_ * NV_ + 255) / 256, 256, 0, stream>>>(cam, verts, vp);
  dim3 bgrid(NBLK_, B_);
  facebin_k<<<bgrid, FBF_, 0, stream>>>(cam, vp, faces, recs, cntb);
  sum_k<<<dim3(NCELL_ / 256, B_), 256, 0, stream>>>(cntb, cnt8);
  scan_k<<<1, NBIN_, 0, stream>>>(cnt8, off8, binoff, bintot, work, nC);
  bin_fill_k<<<bgrid, FBF_, 0, stream>>>(recs, off8, cntb, list);
  raster_seed_k<<<NBIN_, 256, 0, stream>>>(vp, faces, list, bintot, binoff,
                                           zkey);
  raster_k<<<MAXC_, 256, 0, stream>>>(vp, faces, list, bintot, binoff, work,
                                      nC, zkey);
  shade_k<<<(B_ * NPIX + 255) / 256, 256, 0, stream>>>(vp, faces, uv, samp,
                                                       zkey, (float*)d_out);
}